// Round 5
// baseline (465.785 us; speedup 1.0000x reference)
//
#include <hip/hip_runtime.h>
#include <math.h>

#define N_TOK 8192
#define DIM   4096
#define NE    16
#define TOKS  (2*N_TOK)        // 16384
#define NCHUNK (TOKS/64)       // 256
#define D4    (DIM/4)          // 1024 float4 per row
#define NSEGG 8                // D seg-groups (512 cols each); part combine depth
#define SLICEF4 128            // float4 per block slice (512 cols)

// d_out layout (all float32):
// [0] l_aux | [1..16384] token_pos_after | [16385..32768] token_pos_before
// [32769..32784] expert_token_count | [32785..49168] weight
#define OUT_LAUX 0
#define OUT_TPA  1
#define OUT_TPB  (1+TOKS)
#define OUT_CNT  (1+2*TOKS)
#define OUT_W    (1+2*TOKS+NE)

// K1 v6 = v5 + VGPR cap + cross-pass prefetch. 1024 blocks x 256 threads.
// v4 failed on spills (VGPR=256, +268MB scratch traffic); v5 fixed spills
// but serialized passes (VGPR=200 -> 2 waves/SIMD, 8 loads then full-stall:
// 7% HBM, 128us). v6 closes both: __launch_bounds__(256,4) caps VGPR at 128
// (4 waves/SIMD = the grid's 4 blocks/CU), and pass j+1's 8 loads are issued
// BEFORE pass j's 512 FMAs + butterfly (~600 VALU cyc); the vmcnt wait lands
// on the xq<-xn register copy at the bottom of the body. Load shape stays
// 4 rows x 256 B contiguous = 4 segments/instr (the m13-copy shape).
__global__ __launch_bounds__(256, 4) void k1_v6(
    const float4* __restrict__ x4, const float4* __restrict__ wg4,
    float* __restrict__ part)
{
    __shared__ float4 wgl[NE][SLICEF4];   // 32 KB  [e][slice f4]

    const int tid  = threadIdx.x;
    const int lane = tid & 63;
    const int w    = tid >> 6;            // 0..3
    const int r    = lane >> 4;           // 0..3  row within pass
    const int c    = lane & 15;           // 0..15 col group
    const int g    = blockIdx.x & 7;      // slice group (512 cols)
    const int rg   = blockIdx.x >> 3;     // row group (64 rows)

    // ---- stage Wg slice: 2048 float4, 8 per thread, coalesced ----
    #pragma unroll
    for (int i = 0; i < 8; ++i) {
        const int idx = i * 256 + tid;
        const int e = idx >> 7, cc = idx & 127;
        wgl[e][cc] = wg4[(size_t)e * D4 + g * SLICEF4 + cc];
    }
    __syncthreads();

    const int rowbase = rg * 64 + w * 16;
    const float4* xbase = x4 + (size_t)(rowbase + r) * D4 + g * SLICEF4 + c;

    // prime pass 0
    float4 xq[8];
    #pragma unroll
    for (int k = 0; k < 8; ++k) xq[k] = xbase[16 * k];

    #pragma unroll 1   // self-contained passes; no compiler mega-pipeline
    for (int j = 0; j < 4; ++j) {
        // ---- prefetch pass j+1 (flies under this pass's FMA block) ----
        float4 xn[8];
        if (j < 3) {
            const float4* xnrow = xbase + (size_t)(j + 1) * 4 * D4;
            #pragma unroll
            for (int k = 0; k < 8; ++k) xn[k] = xnrow[16 * k];
        }

        float v[NE];
        #pragma unroll
        for (int e = 0; e < NE; ++e) v[e] = 0.f;

        #pragma unroll
        for (int k = 0; k < 8; ++k) {
            const float4 xv = xq[k];
            #pragma unroll
            for (int e = 0; e < NE; ++e) {
                const float4 wv = wgl[e][c + 16 * k];  // 16-addr, 2-way banks (free)
                float a = v[e];
                a = fmaf(xv.x, wv.x, a);
                a = fmaf(xv.y, wv.y, a);
                a = fmaf(xv.z, wv.z, a);
                a = fmaf(xv.w, wv.w, a);
                v[e] = a;
            }
        }

        // ---- butterfly reduce across the 16-lane group (verified: absmax=0) ----
        #pragma unroll
        for (int e = 0; e < 8; ++e) {
            const float send = (c & 8) ? v[e] : v[e + 8];
            const float recv = __shfl_xor(send, 8);
            v[e] = ((c & 8) ? v[e + 8] : v[e]) + recv;
        }
        #pragma unroll
        for (int e = 0; e < 4; ++e) {
            const float send = (c & 4) ? v[e] : v[e + 4];
            const float recv = __shfl_xor(send, 4);
            v[e] = ((c & 4) ? v[e + 4] : v[e]) + recv;
        }
        #pragma unroll
        for (int e = 0; e < 2; ++e) {
            const float send = (c & 2) ? v[e] : v[e + 2];
            const float recv = __shfl_xor(send, 2);
            v[e] = ((c & 2) ? v[e + 2] : v[e]) + recv;
        }
        {
            const float send = (c & 1) ? v[0] : v[1];
            const float recv = __shfl_xor(send, 1);
            v[0] = ((c & 1) ? v[1] : v[0]) + recv;
        }

        // wave writes 4 rows x 16 experts = 256 contiguous bytes
        const int row = rowbase + j * 4 + r;
        part[(size_t)g * (N_TOK * NE) + (size_t)row * NE + c] = v[0];

        // consume prefetch; the vmcnt wait lands HERE, after the VALU block
        if (j < 3) {
            #pragma unroll
            for (int k = 0; k < 8; ++k) xq[k] = xn[k];
        }
    }
}

// K2: combine 8 slice partials (fixed order -> deterministic), top-2, softmax,
// weights, me partials, stable intra-chunk ranks + chunk histograms.
// 64 blocks x 128 threads, one thread per row. (round-2 proven config)
__global__ __launch_bounds__(128) void k2_route(
    const float* __restrict__ part, int* __restrict__ pr,
    int* __restrict__ hist, float* __restrict__ me_part,
    float* __restrict__ out)
{
    const int row   = blockIdx.x * 128 + threadIdx.x;
    const int lane  = threadIdx.x & 63;
    const int gwave = row >> 6;   // chunk index for top-1 half, in [0,128)

    float lg[NE];
    #pragma unroll
    for (int e = 0; e < NE; ++e) lg[e] = 0.f;
    const float4* p4 = (const float4*)part;
    #pragma unroll
    for (int s = 0; s < NSEGG; ++s) {
        const size_t base = ((size_t)s * N_TOK + row) * 4;
        #pragma unroll
        for (int q = 0; q < 4; ++q) {
            float4 t = p4[base + q];
            lg[q * 4 + 0] += t.x;
            lg[q * 4 + 1] += t.y;
            lg[q * 4 + 2] += t.z;
            lg[q * 4 + 3] += t.w;
        }
    }

    // top-2; strict > keeps lowest index on ties (matches lax.top_k)
    float m1 = -INFINITY; int i1 = 0;
    #pragma unroll
    for (int e = 0; e < NE; ++e)
        if (lg[e] > m1) { m1 = lg[e]; i1 = e; }
    float m2 = -INFINITY; int i2 = 0;
    #pragma unroll
    for (int e = 0; e < NE; ++e)
        if (e != i1 && lg[e] > m2) { m2 = lg[e]; i2 = e; }

    float ssum = 0.f, ex[NE];
    #pragma unroll
    for (int e = 0; e < NE; ++e) { ex[e] = __expf(lg[e] - m1); ssum += ex[e]; }
    const float inv = 1.f / ssum;

    const float e2v = __expf(m2 - m1);
    const float w1  = 1.f / (1.f + e2v);
    out[OUT_W + row]         = w1;
    out[OUT_W + N_TOK + row] = 1.f - w1;

    // per-wave me partial: butterfly each expert; lane e keeps expert e's sum
    float mymev = 0.f;
    #pragma unroll
    for (int e = 0; e < NE; ++e) {
        float mv = ex[e] * inv;
        mv += __shfl_xor(mv, 32); mv += __shfl_xor(mv, 16);
        mv += __shfl_xor(mv, 8);  mv += __shfl_xor(mv, 4);
        mv += __shfl_xor(mv, 2);  mv += __shfl_xor(mv, 1);
        if (lane == e) mymev = mv;
    }
    if (lane < NE) me_part[gwave * NE + lane] = mymev;

    // stable intra-chunk ranks + chunk histograms via ballot
    const unsigned long long mlt = (1ull << lane) - 1ull;
    int rk1 = 0, rk2 = 0;
    #pragma unroll
    for (int eo = 0; eo < NE; ++eo) {
        unsigned long long mA = __ballot(i1 == eo);
        unsigned long long mB = __ballot(i2 == eo);
        if (i1 == eo) rk1 = (int)__popcll(mA & mlt);
        if (i2 == eo) rk2 = (int)__popcll(mB & mlt);
        if (lane == eo) {
            hist[gwave * NE + eo]                = (int)__popcll(mA);
            hist[(NCHUNK / 2 + gwave) * NE + eo] = (int)__popcll(mB);
        }
    }
    pr[row]         = i1 | (rk1 << 8);
    pr[N_TOK + row] = i2 | (rk2 << 8);
}

// K3: 64 blocks x 256. Every block redundantly scans the 256x16 chunk
// histogram in LDS, then places its 256 tokens. Block 0 adds l_aux + counts.
__global__ __launch_bounds__(256) void k3_place(
    const int* __restrict__ pr, const int* __restrict__ hist,
    const float* __restrict__ me_part, float* __restrict__ out)
{
    __shared__ int   sh[NCHUNK][20];   // padded
    __shared__ int   cnt_sh[NE], ce_sh[NE];
    __shared__ float me_sh[16][17];
    __shared__ float me_tot[NE];

    const int t = threadIdx.x;

    int h[NE];
    {
        const int4* h4 = (const int4*)(hist + t * NE);
        int4 a = h4[0], b = h4[1], c = h4[2], d = h4[3];
        h[0]=a.x; h[1]=a.y; h[2]=a.z; h[3]=a.w;
        h[4]=b.x; h[5]=b.y; h[6]=b.z; h[7]=b.w;
        h[8]=c.x; h[9]=c.y; h[10]=c.z; h[11]=c.w;
        h[12]=d.x; h[13]=d.y; h[14]=d.z; h[15]=d.w;
    }
    #pragma unroll
    for (int e = 0; e < NE; ++e) sh[t][e] = h[e];
    __syncthreads();

    for (int off = 1; off < NCHUNK; off <<= 1) {
        int tmp[NE];
        #pragma unroll
        for (int e = 0; e < NE; ++e) tmp[e] = (t >= off) ? sh[t - off][e] : 0;
        __syncthreads();
        #pragma unroll
        for (int e = 0; e < NE; ++e) sh[t][e] += tmp[e];
        __syncthreads();
    }

    if (t == NCHUNK - 1) {
        #pragma unroll
        for (int e = 0; e < NE; ++e) cnt_sh[e] = sh[t][e];
    }
    if (t == NCHUNK / 2 - 1) {
        #pragma unroll
        for (int e = 0; e < NE; ++e) ce_sh[e] = sh[t][e];  // top-1 totals
    }

    int ex[NE];
    #pragma unroll
    for (int e = 0; e < NE; ++e) ex[e] = sh[t][e] - h[e];
    __syncthreads();
    #pragma unroll
    for (int e = 0; e < NE; ++e) sh[t][e] = ex[e];
    __syncthreads();

    int offs[NE];
    {
        int run = 0;
        #pragma unroll
        for (int e = 0; e < NE; ++e) { offs[e] = run; run += cnt_sh[e]; }
    }

    {
        const int tk = blockIdx.x * 256 + t;
        const int v  = pr[tk];
        const int e  = v & 255;
        const int rk = v >> 8;
        const int c  = tk >> 6;
        const int pos = sh[c][e] + offs[e] + rk;
        out[OUT_TPA + tk]  = (float)pos;
        out[OUT_TPB + pos] = (float)tk;
    }

    if (blockIdx.x == 0) {
        {
            const int e = t & 15, gg = t >> 4;   // gg in [0,16)
            float s = 0.f;
            #pragma unroll
            for (int k = 0; k < 8; ++k) s += me_part[(gg + 16 * k) * NE + e];
            me_sh[gg][e] = s;
        }
        __syncthreads();
        if (t < NE) {
            float me = 0.f;
            #pragma unroll
            for (int gg = 0; gg < 16; ++gg) me += me_sh[gg][t];
            me_tot[t] = me;
            out[OUT_CNT + t] = (float)cnt_sh[t];
        }
        __syncthreads();
        if (t == 0) {
            float la = 0.f;
            #pragma unroll
            for (int e = 0; e < NE; ++e)
                la += (me_tot[e] * (1.0f / N_TOK)) * ((float)ce_sh[e] * (1.0f / N_TOK));
            out[OUT_LAUX] = la * (float)NE;
        }
    }
}

extern "C" void kernel_launch(void* const* d_in, const int* in_sizes, int n_in,
                              void* d_out, int out_size, void* d_ws, size_t ws_size,
                              hipStream_t stream) {
    const float* x  = (const float*)d_in[0];   // [8192,4096] fp32
    const float* wg = (const float*)d_in[1];   // [16,4096] fp32
    float* out = (float*)d_out;

    char* w = (char*)d_ws;
    float* part    = (float*)w;  w += (size_t)NSEGG * N_TOK * NE * sizeof(float); // 4 MB
    int*   pr      = (int*)w;    w += TOKS * sizeof(int);         // 64 KB
    int*   hist    = (int*)w;    w += NCHUNK * NE * sizeof(int);  // 16 KB
    float* me_part = (float*)w;                                   // 8 KB

    k1_v6<<<(N_TOK / 64) * NSEGG, 256, 0, stream>>>(
        (const float4*)x, (const float4*)wg, part);
    k2_route<<<N_TOK / 128, 128, 0, stream>>>(part, pr, hist, me_part, out);
    k3_place<<<TOKS / 256, 256, 0, stream>>>(pr, hist, me_part, out);
}

// Round 6
// 210.425 us; speedup vs baseline: 2.2135x; 2.2135x over previous
//
#include <hip/hip_runtime.h>
#include <math.h>

#define N_TOK 8192
#define DIM   4096
#define NE    16
#define TOKS  (2*N_TOK)        // 16384
#define NCHUNK (TOKS/64)       // 256
#define D4    (DIM/4)          // 1024 float4 per row
#define NSEGG 16               // D seg-groups (256 cols each); part combine depth
#define SLICEF4 64             // float4 per block slice (256 cols)

// d_out layout (all float32):
// [0] l_aux | [1..16384] token_pos_after | [16385..32768] token_pos_before
// [32769..32784] expert_token_count | [32785..49168] weight
#define OUT_LAUX 0
#define OUT_TPA  1
#define OUT_TPB  (1+TOKS)
#define OUT_CNT  (1+2*TOKS)
#define OUT_W    (1+2*TOKS+NE)

// K1 v7 = v3 (round-2 winner, 209.7us) with NSEGG 8->16: same 4-lane-group
// layout, same butterfly+select ending, same compiler freedom (no
// launch_bounds, no unroll pragmas -- v4/v5/v6 showed every constraint
// backfires). Only the slice shrinks to 256 cols: 2048 blocks (2x resident
// blocks/CU for latency hiding), 16 KB LDS, per-lane x footprint halves to
// 16 float4 (xq[8] x 2 passes) -> lower VGPR, shorter stall chains.
// Tests the hypothesis that v3's k1 (~60us vs ~21us HBM floor) is
// latency-exposed at 4 blocks/CU.
__global__ __launch_bounds__(256) void k1_v7(
    const float4* __restrict__ x4, const float4* __restrict__ wg4,
    float* __restrict__ part)
{
    __shared__ float4 wgl[NE][SLICEF4];   // 16 KB  [e][slice f4]

    const int tid  = threadIdx.x;
    const int lane = tid & 63;
    const int w    = tid >> 6;            // 0..3
    const int r    = lane >> 2;           // 0..15 row within wave
    const int c    = lane & 3;            // 0..3  col group
    const int g    = blockIdx.x & 15;     // slice group (256 cols)
    const int rg   = blockIdx.x >> 4;     // row group (64 rows)

    // ---- stage Wg slice: 1024 float4, 4 per thread, coalesced ----
    #pragma unroll
    for (int i = 0; i < 4; ++i) {
        const int idx = i * 256 + tid;
        const int e = idx >> 6, cc = idx & 63;
        wgl[e][cc] = wg4[(size_t)e * D4 + g * SLICEF4 + cc];
    }
    __syncthreads();

    const int row = rg * 64 + w * 16 + r;
    const float4* xrow = x4 + (size_t)row * D4 + g * SLICEF4 + c;

    float acc[NE];
    #pragma unroll
    for (int e = 0; e < NE; ++e) acc[e] = 0.f;

    #pragma unroll
    for (int si = 0; si < 2; ++si) {
        float4 xq[8];
        #pragma unroll
        for (int k = 0; k < 8; ++k) xq[k] = xrow[4 * (si * 8 + k)];
        #pragma unroll
        for (int e = 0; e < NE; ++e) {
            float a = acc[e];
            #pragma unroll
            for (int k = 0; k < 8; ++k) {
                const float4 wv = wgl[e][c + 4 * (si * 8 + k)]; // 4-addr broadcast
                a = fmaf(xq[k].x, wv.x, a);
                a = fmaf(xq[k].y, wv.y, a);
                a = fmaf(xq[k].z, wv.z, a);
                a = fmaf(xq[k].w, wv.w, a);
            }
            acc[e] = a;
        }
    }

    // ---- finish dot products across the 4-lane group ----
    float red[NE];
    #pragma unroll
    for (int e = 0; e < NE; ++e) {
        float v = acc[e];
        v += __shfl_xor(v, 1);
        v += __shfl_xor(v, 2);
        red[e] = v;            // all 4 lanes of the group hold the sum
    }

    // lane (r,c) stores experts 4c..4c+3 as one float4:
    // part word addr = g*131072 + row*16 + 4c  -> contiguous 64 B per row
    float4 o;
    o.x = (c == 0) ? red[0] : (c == 1) ? red[4] : (c == 2) ? red[8]  : red[12];
    o.y = (c == 0) ? red[1] : (c == 1) ? red[5] : (c == 2) ? red[9]  : red[13];
    o.z = (c == 0) ? red[2] : (c == 1) ? red[6] : (c == 2) ? red[10] : red[14];
    o.w = (c == 0) ? red[3] : (c == 1) ? red[7] : (c == 2) ? red[11] : red[15];
    ((float4*)part)[(size_t)g * (N_TOK * 4) + (size_t)row * 4 + c] = o;
}

// K2: combine 16 slice partials (fixed order -> deterministic), top-2, softmax,
// weights, me partials, stable intra-chunk ranks + chunk histograms.
// 64 blocks x 128 threads, one thread per row. (round-2 proven config)
__global__ __launch_bounds__(128) void k2_route(
    const float* __restrict__ part, int* __restrict__ pr,
    int* __restrict__ hist, float* __restrict__ me_part,
    float* __restrict__ out)
{
    const int row   = blockIdx.x * 128 + threadIdx.x;
    const int lane  = threadIdx.x & 63;
    const int gwave = row >> 6;   // chunk index for top-1 half, in [0,128)

    float lg[NE];
    #pragma unroll
    for (int e = 0; e < NE; ++e) lg[e] = 0.f;
    const float4* p4 = (const float4*)part;
    #pragma unroll
    for (int s = 0; s < NSEGG; ++s) {
        const size_t base = ((size_t)s * N_TOK + row) * 4;
        #pragma unroll
        for (int q = 0; q < 4; ++q) {
            float4 t = p4[base + q];
            lg[q * 4 + 0] += t.x;
            lg[q * 4 + 1] += t.y;
            lg[q * 4 + 2] += t.z;
            lg[q * 4 + 3] += t.w;
        }
    }

    // top-2; strict > keeps lowest index on ties (matches lax.top_k)
    float m1 = -INFINITY; int i1 = 0;
    #pragma unroll
    for (int e = 0; e < NE; ++e)
        if (lg[e] > m1) { m1 = lg[e]; i1 = e; }
    float m2 = -INFINITY; int i2 = 0;
    #pragma unroll
    for (int e = 0; e < NE; ++e)
        if (e != i1 && lg[e] > m2) { m2 = lg[e]; i2 = e; }

    float ssum = 0.f, ex[NE];
    #pragma unroll
    for (int e = 0; e < NE; ++e) { ex[e] = __expf(lg[e] - m1); ssum += ex[e]; }
    const float inv = 1.f / ssum;

    const float e2v = __expf(m2 - m1);
    const float w1  = 1.f / (1.f + e2v);
    out[OUT_W + row]         = w1;
    out[OUT_W + N_TOK + row] = 1.f - w1;

    // per-wave me partial: butterfly each expert; lane e keeps expert e's sum
    float mymev = 0.f;
    #pragma unroll
    for (int e = 0; e < NE; ++e) {
        float mv = ex[e] * inv;
        mv += __shfl_xor(mv, 32); mv += __shfl_xor(mv, 16);
        mv += __shfl_xor(mv, 8);  mv += __shfl_xor(mv, 4);
        mv += __shfl_xor(mv, 2);  mv += __shfl_xor(mv, 1);
        if (lane == e) mymev = mv;
    }
    if (lane < NE) me_part[gwave * NE + lane] = mymev;

    // stable intra-chunk ranks + chunk histograms via ballot
    const unsigned long long mlt = (1ull << lane) - 1ull;
    int rk1 = 0, rk2 = 0;
    #pragma unroll
    for (int eo = 0; eo < NE; ++eo) {
        unsigned long long mA = __ballot(i1 == eo);
        unsigned long long mB = __ballot(i2 == eo);
        if (i1 == eo) rk1 = (int)__popcll(mA & mlt);
        if (i2 == eo) rk2 = (int)__popcll(mB & mlt);
        if (lane == eo) {
            hist[gwave * NE + eo]                = (int)__popcll(mA);
            hist[(NCHUNK / 2 + gwave) * NE + eo] = (int)__popcll(mB);
        }
    }
    pr[row]         = i1 | (rk1 << 8);
    pr[N_TOK + row] = i2 | (rk2 << 8);
}

// K3: 64 blocks x 256. Every block redundantly scans the 256x16 chunk
// histogram in LDS, then places its 256 tokens. Block 0 adds l_aux + counts.
__global__ __launch_bounds__(256) void k3_place(
    const int* __restrict__ pr, const int* __restrict__ hist,
    const float* __restrict__ me_part, float* __restrict__ out)
{
    __shared__ int   sh[NCHUNK][20];   // padded
    __shared__ int   cnt_sh[NE], ce_sh[NE];
    __shared__ float me_sh[16][17];
    __shared__ float me_tot[NE];

    const int t = threadIdx.x;

    int h[NE];
    {
        const int4* h4 = (const int4*)(hist + t * NE);
        int4 a = h4[0], b = h4[1], c = h4[2], d = h4[3];
        h[0]=a.x; h[1]=a.y; h[2]=a.z; h[3]=a.w;
        h[4]=b.x; h[5]=b.y; h[6]=b.z; h[7]=b.w;
        h[8]=c.x; h[9]=c.y; h[10]=c.z; h[11]=c.w;
        h[12]=d.x; h[13]=d.y; h[14]=d.z; h[15]=d.w;
    }
    #pragma unroll
    for (int e = 0; e < NE; ++e) sh[t][e] = h[e];
    __syncthreads();

    for (int off = 1; off < NCHUNK; off <<= 1) {
        int tmp[NE];
        #pragma unroll
        for (int e = 0; e < NE; ++e) tmp[e] = (t >= off) ? sh[t - off][e] : 0;
        __syncthreads();
        #pragma unroll
        for (int e = 0; e < NE; ++e) sh[t][e] += tmp[e];
        __syncthreads();
    }

    if (t == NCHUNK - 1) {
        #pragma unroll
        for (int e = 0; e < NE; ++e) cnt_sh[e] = sh[t][e];
    }
    if (t == NCHUNK / 2 - 1) {
        #pragma unroll
        for (int e = 0; e < NE; ++e) ce_sh[e] = sh[t][e];  // top-1 totals
    }

    int ex[NE];
    #pragma unroll
    for (int e = 0; e < NE; ++e) ex[e] = sh[t][e] - h[e];
    __syncthreads();
    #pragma unroll
    for (int e = 0; e < NE; ++e) sh[t][e] = ex[e];
    __syncthreads();

    int offs[NE];
    {
        int run = 0;
        #pragma unroll
        for (int e = 0; e < NE; ++e) { offs[e] = run; run += cnt_sh[e]; }
    }

    {
        const int tk = blockIdx.x * 256 + t;
        const int v  = pr[tk];
        const int e  = v & 255;
        const int rk = v >> 8;
        const int c  = tk >> 6;
        const int pos = sh[c][e] + offs[e] + rk;
        out[OUT_TPA + tk]  = (float)pos;
        out[OUT_TPB + pos] = (float)tk;
    }

    if (blockIdx.x == 0) {
        {
            const int e = t & 15, gg = t >> 4;   // gg in [0,16)
            float s = 0.f;
            #pragma unroll
            for (int k = 0; k < 8; ++k) s += me_part[(gg + 16 * k) * NE + e];
            me_sh[gg][e] = s;
        }
        __syncthreads();
        if (t < NE) {
            float me = 0.f;
            #pragma unroll
            for (int gg = 0; gg < 16; ++gg) me += me_sh[gg][t];
            me_tot[t] = me;
            out[OUT_CNT + t] = (float)cnt_sh[t];
        }
        __syncthreads();
        if (t == 0) {
            float la = 0.f;
            #pragma unroll
            for (int e = 0; e < NE; ++e)
                la += (me_tot[e] * (1.0f / N_TOK)) * ((float)ce_sh[e] * (1.0f / N_TOK));
            out[OUT_LAUX] = la * (float)NE;
        }
    }
}

extern "C" void kernel_launch(void* const* d_in, const int* in_sizes, int n_in,
                              void* d_out, int out_size, void* d_ws, size_t ws_size,
                              hipStream_t stream) {
    const float* x  = (const float*)d_in[0];   // [8192,4096] fp32
    const float* wg = (const float*)d_in[1];   // [16,4096] fp32
    float* out = (float*)d_out;

    char* w = (char*)d_ws;
    float* part    = (float*)w;  w += (size_t)NSEGG * N_TOK * NE * sizeof(float); // 8 MB
    int*   pr      = (int*)w;    w += TOKS * sizeof(int);         // 64 KB
    int*   hist    = (int*)w;    w += NCHUNK * NE * sizeof(int);  // 16 KB
    float* me_part = (float*)w;                                   // 8 KB

    k1_v7<<<(N_TOK / 64) * NSEGG, 256, 0, stream>>>(
        (const float4*)x, (const float4*)wg, part);
    k2_route<<<N_TOK / 128, 128, 0, stream>>>(part, pr, hist, me_part, out);
    k3_place<<<TOKS / 256, 256, 0, stream>>>(pr, hist, me_part, out);
}